// Round 4
// baseline (894.117 us; speedup 1.0000x reference)
//
#include <hip/hip_runtime.h>
#include <hip/hip_bf16.h>

// Problem constants (reference: T=8192, H=1024, I=2816, E=8)
#define T_TOK 8192
#define H_DIM 1024
#define I_DIM 2816
#define E_EXP 8

#define BM 128
#define BN 128
#define BK 32
#define MAXTILES (T_TOK / BM + E_EXP) // 72 worst case

typedef __bf16 bf16x8 __attribute__((ext_vector_type(8)));
typedef float f32x4 __attribute__((ext_vector_type(4)));

// swizzled LDS byte offset for a [rows][BK=32 bf16] tile; row stride = 64B.
// involution: 16B-chunk index ^= (row>>1)&3  (2-way bank aliasing only = free)
#define SWZ32(r, bc) (((r) * 64) + ((bc) ^ ((((r) >> 1) & 3) << 4)))

__device__ __forceinline__ void gload16(const void* g, void* l) {
  __builtin_amdgcn_global_load_lds((const __attribute__((address_space(1))) void*)g,
                                   (__attribute__((address_space(3))) void*)l, 16, 0, 0);
}

__device__ __forceinline__ bf16x8 cvt8(const float4& p0, const float4& p1) {
  bf16x8 v;
  v[0] = (__bf16)p0.x; v[1] = (__bf16)p0.y; v[2] = (__bf16)p0.z; v[3] = (__bf16)p0.w;
  v[4] = (__bf16)p1.x; v[5] = (__bf16)p1.y; v[6] = (__bf16)p1.z; v[7] = (__bf16)p1.w;
  return v;
}

// ---------------- bucketing kernels ----------------
__global__ void k_count(const int* __restrict__ idx, int* __restrict__ counts) {
  int t = blockIdx.x * blockDim.x + threadIdx.x;
  if (t < T_TOK) atomicAdd(&counts[idx[t]], 1);
}

__global__ void k_tiles(const int* __restrict__ counts, int* __restrict__ offsets,
                        int* __restrict__ tE, int* __restrict__ tB,
                        int* __restrict__ tEnd, int* __restrict__ nT) {
  if (threadIdx.x != 0 || blockIdx.x != 0) return;
  int off = 0, nt = 0;
  for (int e = 0; e < E_EXP; ++e) {
    offsets[e] = off;
    int c = counts[e];
    for (int b = 0; b < c; b += BM) { tE[nt] = e; tB[nt] = off + b; tEnd[nt] = off + c; ++nt; }
    off += c;
  }
  offsets[E_EXP] = off;
  *nT = nt;
}

__global__ void k_scatter(const int* __restrict__ idx, const int* __restrict__ offsets,
                          int* __restrict__ cursor, int* __restrict__ order) {
  int t = blockIdx.x * blockDim.x + threadIdx.x;
  if (t < T_TOK) {
    int e = idx[t];
    int p = offsets[e] + atomicAdd(&cursor[e], 1);
    order[p] = t;
  }
}

// ---------------- bf16 pre-conversion ----------------
__global__ __launch_bounds__(256) void k_cvt(const float* __restrict__ src,
                                             __bf16* __restrict__ dst, int n8) {
  int i = blockIdx.x * blockDim.x + threadIdx.x;
  if (i < n8) {
    const float4 p0 = ((const float4*)src)[i * 2];
    const float4 p1 = ((const float4*)src)[i * 2 + 1];
    ((bf16x8*)dst)[i] = cvt8(p0, p1);
  }
}

// gather by order + convert x -> xp (bf16, permuted rows)
__global__ __launch_bounds__(128) void k_xperm(const float* __restrict__ x,
                                               const int* __restrict__ order,
                                               __bf16* __restrict__ xp) {
  const int row = blockIdx.x;
  const int tok = order[row];
  const float* s = x + (size_t)tok * H_DIM + threadIdx.x * 8;
  const float4 p0 = ((const float4*)s)[0];
  const float4 p1 = ((const float4*)s)[1];
  *(bf16x8*)(xp + (size_t)row * H_DIM + threadIdx.x * 8) = cvt8(p0, p1);
}

// =====================================================================
// pass 2: gate/up GEMM + silu*mul -> hp
// BK=32 double-buffered, 48KB static LDS -> 3 blocks/CU (24 waves/CU)
// 8 waves as 2(M) x 4(N); wave tile 64 x 32, dual-op (gate+up share A)
// =====================================================================
__global__ __launch_bounds__(512, 6) void k_gateup4(
    const __bf16* __restrict__ xp, const __bf16* __restrict__ wg, const __bf16* __restrict__ wu,
    const int* __restrict__ tE, const int* __restrict__ tB,
    const int* __restrict__ tEnd, const int* __restrict__ nT, __bf16* __restrict__ hp) {
  const int tile = blockIdx.y;
  if (tile >= *nT) return;
  const int e = tE[tile];
  const int rowbase = tB[tile];
  const int rowEnd = tEnd[tile];
  const int nbase = blockIdx.x * BN;

  __shared__ __align__(16) unsigned char smA[2][8192];
  __shared__ __align__(16) unsigned char smG[2][8192];
  __shared__ __align__(16) unsigned char smU[2][8192];

  const int tid = threadIdx.x;
  const int lane = tid & 63;
  const int w = tid >> 6;            // 0..7
  const int wm = w & 1, wn = w >> 1; // 2 x 4 wave grid

  // staging: thread stages 16B per operand per step at LDS linear off tid*16
  // (row = tid>>2, chunk = tid&3); global source chunk pre-swizzled so that
  // swizzled ds_read (SWZ32) recovers linear data. 512 thr x 16B = 8KB tile.
  const int srow = tid >> 2;                       // 0..127
  const int schunk = (tid & 3) ^ ((tid >> 3) & 3); // = (chunk) ^ ((row>>1)&3)
  const __bf16* aS = xp + (size_t)(rowbase + srow) * H_DIM + schunk * 8;
  const __bf16* gS = wg + ((size_t)e * I_DIM + nbase + srow) * H_DIM + schunk * 8;
  const __bf16* uS = wu + ((size_t)e * I_DIM + nbase + srow) * H_DIM + schunk * 8;
  const int ldst = w * 1024; // wave-uniform LDS base (lane*16 implicit)

  f32x4 accg[4][2], accu[4][2];
#pragma unroll
  for (int m = 0; m < 4; ++m)
#pragma unroll
    for (int n = 0; n < 2; ++n)
#pragma unroll
      for (int j = 0; j < 4; ++j) { accg[m][n][j] = 0.f; accu[m][n][j] = 0.f; }

  const int nK = H_DIM / BK; // 32
  // prologue: stage step 0 into buffer 0
  gload16(aS, &smA[0][ldst]);
  gload16(gS, &smG[0][ldst]);
  gload16(uS, &smU[0][ldst]);
  __syncthreads();

  int cur = 0;
  for (int kt = 0; kt < nK; ++kt) {
    if (kt + 1 < nK) { // prefetch next step (hidden under MFMA below)
      const int kof = (kt + 1) * BK;
      gload16(aS + kof, &smA[cur ^ 1][ldst]);
      gload16(gS + kof, &smG[cur ^ 1][ldst]);
      gload16(uS + kof, &smU[cur ^ 1][ldst]);
    }
    bf16x8 a[4], bg[2], bu[2];
    const int kc = (lane >> 4) * 16; // 16B k-chunk within 64B row
#pragma unroll
    for (int m = 0; m < 4; ++m) {
      const int r = wm * 64 + m * 16 + (lane & 15);
      a[m] = *(const bf16x8*)(&smA[cur][0] + SWZ32(r, kc));
    }
#pragma unroll
    for (int n = 0; n < 2; ++n) {
      const int r = wn * 32 + n * 16 + (lane & 15);
      bg[n] = *(const bf16x8*)(&smG[cur][0] + SWZ32(r, kc));
      bu[n] = *(const bf16x8*)(&smU[cur][0] + SWZ32(r, kc));
    }
#pragma unroll
    for (int m = 0; m < 4; ++m)
#pragma unroll
      for (int n = 0; n < 2; ++n) {
        accg[m][n] = __builtin_amdgcn_mfma_f32_16x16x32_bf16(a[m], bg[n], accg[m][n], 0, 0, 0);
        accu[m][n] = __builtin_amdgcn_mfma_f32_16x16x32_bf16(a[m], bu[n], accu[m][n], 0, 0, 0);
      }
    __syncthreads(); // prefetch arrived + all reads of cur done
    cur ^= 1;
  }

  // epilogue: h = silu(g)*u -> hp (bf16, permuted row layout)
#pragma unroll
  for (int m = 0; m < 4; ++m) {
    const int row0 = wm * 64 + m * 16 + (lane >> 4) * 4;
#pragma unroll
    for (int j = 0; j < 4; ++j) {
      const int gr = rowbase + row0 + j;
      if (gr < rowEnd) {
        __bf16* dst = hp + (size_t)gr * I_DIM + nbase;
#pragma unroll
        for (int n = 0; n < 2; ++n) {
          const int col = wn * 32 + n * 16 + (lane & 15);
          const float g = accg[m][n][j];
          const float u = accu[m][n][j];
          dst[col] = (__bf16)(g / (1.f + __expf(-g)) * u);
        }
      }
    }
  }
}

// =====================================================================
// pass 3: down GEMM, scatter rows to out
// BK=32 double-buffered, 32KB static LDS -> 4 blocks/CU (32 waves/CU)
// =====================================================================
__global__ __launch_bounds__(512, 8) void k_down4(
    const __bf16* __restrict__ hp, const __bf16* __restrict__ wd,
    const int* __restrict__ order, const int* __restrict__ tE, const int* __restrict__ tB,
    const int* __restrict__ tEnd, const int* __restrict__ nT, float* __restrict__ out) {
  const int tile = blockIdx.y;
  if (tile >= *nT) return;
  const int e = tE[tile];
  const int rowbase = tB[tile];
  const int rowEnd = tEnd[tile];
  const int nbase = blockIdx.x * BN; // over H

  __shared__ __align__(16) unsigned char smA[2][8192];
  __shared__ __align__(16) unsigned char smB[2][8192];

  const int tid = threadIdx.x;
  const int lane = tid & 63;
  const int w = tid >> 6;
  const int wm = w & 1, wn = w >> 1; // wave tile 64 x 32

  const int srow = tid >> 2;
  const int schunk = (tid & 3) ^ ((tid >> 3) & 3);
  const __bf16* aS = hp + (size_t)(rowbase + srow) * I_DIM + schunk * 8;
  const __bf16* bS = wd + ((size_t)e * H_DIM + nbase + srow) * I_DIM + schunk * 8;
  const int ldst = w * 1024;

  f32x4 acc[4][2];
#pragma unroll
  for (int m = 0; m < 4; ++m)
#pragma unroll
    for (int n = 0; n < 2; ++n)
#pragma unroll
      for (int j = 0; j < 4; ++j) acc[m][n][j] = 0.f;

  const int nK = I_DIM / BK; // 88
  gload16(aS, &smA[0][ldst]);
  gload16(bS, &smB[0][ldst]);
  __syncthreads();

  int cur = 0;
  for (int kt = 0; kt < nK; ++kt) {
    if (kt + 1 < nK) {
      const int kof = (kt + 1) * BK;
      gload16(aS + kof, &smA[cur ^ 1][ldst]);
      gload16(bS + kof, &smB[cur ^ 1][ldst]);
    }
    bf16x8 a[4], b[2];
    const int kc = (lane >> 4) * 16;
#pragma unroll
    for (int m = 0; m < 4; ++m) {
      const int r = wm * 64 + m * 16 + (lane & 15);
      a[m] = *(const bf16x8*)(&smA[cur][0] + SWZ32(r, kc));
    }
#pragma unroll
    for (int n = 0; n < 2; ++n) {
      const int r = wn * 32 + n * 16 + (lane & 15);
      b[n] = *(const bf16x8*)(&smB[cur][0] + SWZ32(r, kc));
    }
#pragma unroll
    for (int m = 0; m < 4; ++m)
#pragma unroll
      for (int n = 0; n < 2; ++n)
        acc[m][n] = __builtin_amdgcn_mfma_f32_16x16x32_bf16(a[m], b[n], acc[m][n], 0, 0, 0);
    __syncthreads();
    cur ^= 1;
  }

  // epilogue: scatter rows to out[token]
#pragma unroll
  for (int m = 0; m < 4; ++m) {
    const int row0 = wm * 64 + m * 16 + (lane >> 4) * 4;
#pragma unroll
    for (int j = 0; j < 4; ++j) {
      const int gr = rowbase + row0 + j;
      if (gr < rowEnd) {
        const int tok = order[gr];
        float* dst = out + (size_t)tok * H_DIM + nbase;
#pragma unroll
        for (int n = 0; n < 2; ++n) {
          const int col = wn * 32 + n * 16 + (lane & 15);
          dst[col] = acc[m][n][j];
        }
      }
    }
  }
}

// ---------------- launch ----------------
extern "C" void kernel_launch(void* const* d_in, const int* in_sizes, int n_in,
                              void* d_out, int out_size, void* d_ws, size_t ws_size,
                              hipStream_t stream) {
  const float* x = (const float*)d_in[0];
  const int* eidx = (const int*)d_in[1];
  const float* Wg = (const float*)d_in[2];
  const float* Wu = (const float*)d_in[3];
  const float* Wd = (const float*)d_in[4];
  float* out = (float*)d_out;

  char* ws = (char*)d_ws;
  size_t off = 0;
  auto alloc = [&](size_t bytes) -> void* {
    void* p = ws + off;
    off = (off + bytes + 255) & ~(size_t)255;
    return p;
  };
  const size_t TPAD = T_TOK + BM; // tile overreads stay within +128 rows
  __bf16* hp = (__bf16*)alloc(TPAD * I_DIM * sizeof(__bf16));
  int* order = (int*)alloc(T_TOK * sizeof(int));
  int* offsets = (int*)alloc((E_EXP + 1) * sizeof(int));
  int* tE = (int*)alloc(MAXTILES * sizeof(int));
  int* tB = (int*)alloc(MAXTILES * sizeof(int));
  int* tEnd = (int*)alloc(MAXTILES * sizeof(int));
  int* nT = (int*)alloc(sizeof(int));
  int* cc = (int*)alloc(2 * E_EXP * sizeof(int)); // counts | cursor
  int* counts = cc;
  int* cursor = cc + E_EXP;

  const size_t WSZ = (size_t)E_EXP * I_DIM * H_DIM; // elements per weight tensor
  __bf16* xp = (__bf16*)alloc(TPAD * H_DIM * sizeof(__bf16));
  __bf16* wg16 = (__bf16*)alloc(WSZ * sizeof(__bf16));
  __bf16* wu16 = (__bf16*)alloc(WSZ * sizeof(__bf16));
  __bf16* wd16 = (__bf16*)alloc(WSZ * sizeof(__bf16));

  hipMemsetAsync(cc, 0, 2 * E_EXP * sizeof(int), stream);
  k_count<<<T_TOK / 256, 256, 0, stream>>>(eidx, counts);
  k_tiles<<<1, 1, 0, stream>>>(counts, offsets, tE, tB, tEnd, nT);
  k_scatter<<<T_TOK / 256, 256, 0, stream>>>(eidx, offsets, cursor, order);

  const int n8 = (int)(WSZ / 8);
  k_cvt<<<(n8 + 255) / 256, 256, 0, stream>>>(Wg, wg16, n8);
  k_cvt<<<(n8 + 255) / 256, 256, 0, stream>>>(Wu, wu16, n8);
  k_cvt<<<(n8 + 255) / 256, 256, 0, stream>>>(Wd, wd16, n8);
  k_xperm<<<T_TOK, 128, 0, stream>>>(x, order, xp);

  k_gateup4<<<dim3(I_DIM / BN, MAXTILES), 512, 0, stream>>>(xp, wg16, wu16, tE, tB, tEnd, nT, hp);
  k_down4<<<dim3(H_DIM / BN, MAXTILES), 512, 0, stream>>>(hp, wd16, order, tE, tB, tEnd, nT, out);
}

// Round 5
// 386.104 us; speedup vs baseline: 2.3157x; 2.3157x over previous
//
#include <hip/hip_runtime.h>
#include <hip/hip_bf16.h>

// Problem constants (reference: T=8192, H=1024, I=2816, E=8)
#define T_TOK 8192
#define H_DIM 1024
#define I_DIM 2816
#define E_EXP 8

#define BM 256
#define BN 128
#define BK 64
#define MAXTILES (T_TOK / BM + E_EXP) // 40 worst case

typedef __bf16 bf16x8 __attribute__((ext_vector_type(8)));
typedef float f32x4 __attribute__((ext_vector_type(4)));

// swizzled LDS byte offset for a [rows][BK=64 bf16] tile; row stride = 128B
#define SWZ(r, bc) (((r) * (BK * 2)) + (((bc) ^ (((r) & 7) << 4))))

__device__ __forceinline__ void gload16(const void* g, void* l) {
  __builtin_amdgcn_global_load_lds((const __attribute__((address_space(1))) void*)g,
                                   (__attribute__((address_space(3))) void*)l, 16, 0, 0);
}

__device__ __forceinline__ bf16x8 cvt8(const float4& p0, const float4& p1) {
  bf16x8 v;
  v[0] = (__bf16)p0.x; v[1] = (__bf16)p0.y; v[2] = (__bf16)p0.z; v[3] = (__bf16)p0.w;
  v[4] = (__bf16)p1.x; v[5] = (__bf16)p1.y; v[6] = (__bf16)p1.z; v[7] = (__bf16)p1.w;
  return v;
}

// ---------------- bucketing kernels ----------------
__global__ void k_count(const int* __restrict__ idx, int* __restrict__ counts) {
  int t = blockIdx.x * blockDim.x + threadIdx.x;
  if (t < T_TOK) atomicAdd(&counts[idx[t]], 1);
}

__global__ void k_tiles(const int* __restrict__ counts, int* __restrict__ offsets,
                        int* __restrict__ tE, int* __restrict__ tB,
                        int* __restrict__ tEnd, int* __restrict__ nT) {
  if (threadIdx.x != 0 || blockIdx.x != 0) return;
  int off = 0, nt = 0;
  for (int e = 0; e < E_EXP; ++e) {
    offsets[e] = off;
    int c = counts[e];
    for (int b = 0; b < c; b += BM) { tE[nt] = e; tB[nt] = off + b; tEnd[nt] = off + c; ++nt; }
    off += c;
  }
  offsets[E_EXP] = off;
  *nT = nt;
}

__global__ void k_scatter(const int* __restrict__ idx, const int* __restrict__ offsets,
                          int* __restrict__ cursor, int* __restrict__ order) {
  int t = blockIdx.x * blockDim.x + threadIdx.x;
  if (t < T_TOK) {
    int e = idx[t];
    int p = offsets[e] + atomicAdd(&cursor[e], 1);
    order[p] = t;
  }
}

// ---------------- bf16 pre-conversion ----------------
__global__ __launch_bounds__(256) void k_cvt(const float* __restrict__ src,
                                             __bf16* __restrict__ dst, int n8) {
  int i = blockIdx.x * blockDim.x + threadIdx.x;
  if (i < n8) {
    const float4 p0 = ((const float4*)src)[i * 2];
    const float4 p1 = ((const float4*)src)[i * 2 + 1];
    ((bf16x8*)dst)[i] = cvt8(p0, p1);
  }
}

// gather by order + convert x -> xp (bf16, permuted rows)
__global__ __launch_bounds__(128) void k_xperm(const float* __restrict__ x,
                                               const int* __restrict__ order,
                                               __bf16* __restrict__ xp) {
  const int row = blockIdx.x;
  const int tok = order[row];
  const float* s = x + (size_t)tok * H_DIM + threadIdx.x * 8;
  const float4 p0 = ((const float4*)s)[0];
  const float4 p1 = ((const float4*)s)[1];
  *(bf16x8*)(xp + (size_t)row * H_DIM + threadIdx.x * 8) = cvt8(p0, p1);
}

// =====================================================================
// pass 2: gate/up GEMM + silu*mul -> hp
// BM=256 x BN=128, BK=64, prefetch double-buffered; 128KB dynamic LDS,
// 1 block/CU, 8 waves as 4(M) x 2(N), wave tile 64x64, dual-op.
// =====================================================================
__global__ __launch_bounds__(512, 2) void k_gateup5(
    const __bf16* __restrict__ xp, const __bf16* __restrict__ wg, const __bf16* __restrict__ wu,
    const int* __restrict__ tE, const int* __restrict__ tB,
    const int* __restrict__ tEnd, const int* __restrict__ nT, __bf16* __restrict__ hp) {
  const int tile = blockIdx.y;
  if (tile >= *nT) return;
  const int e = tE[tile];
  const int rowbase = tB[tile];
  const int rowEnd = tEnd[tile];
  const int nbase = blockIdx.x * BN;

  extern __shared__ __align__(16) unsigned char smem[];
  unsigned char* smA = smem;          // [2][32768]  256 x 128B
  unsigned char* smG = smem + 65536;  // [2][16384]  128 x 128B
  unsigned char* smU = smem + 98304;  // [2][16384]

  const int tid = threadIdx.x;
  const int lane = tid & 63;
  const int w = tid >> 6;            // 0..7
  const int wm = w & 3, wn = w >> 2; // 4 x 2 wave grid, wave tile 64x64

  // staging: lane -> row lr=lane>>3 within an 8-row group, source 16B chunk
  // pre-swizzled (global side); LDS dest linear; ds_read applies SWZ().
  const int lr = lane >> 3;
  const int lc = (lane & 7) ^ lr;
  const __bf16* aS[4]; const __bf16* gS[2]; const __bf16* uS[2];
  int adst[4], gdst[2];
#pragma unroll
  for (int r = 0; r < 4; ++r) { // A: 256 rows in 4 rounds of 64
    const int rt = r * 64 + w * 8 + lr;
    aS[r] = xp + (size_t)(rowbase + rt) * H_DIM + lc * 8;
    adst[r] = rt * 128;
  }
#pragma unroll
  for (int r = 0; r < 2; ++r) { // G/U: 128 rows in 2 rounds of 64
    const int rt = r * 64 + w * 8 + lr;
    gS[r] = wg + ((size_t)e * I_DIM + nbase + rt) * H_DIM + lc * 8;
    uS[r] = wu + ((size_t)e * I_DIM + nbase + rt) * H_DIM + lc * 8;
    gdst[r] = rt * 128;
  }

  f32x4 accg[4][4], accu[4][4];
#pragma unroll
  for (int m = 0; m < 4; ++m)
#pragma unroll
    for (int n = 0; n < 4; ++n)
#pragma unroll
      for (int j = 0; j < 4; ++j) { accg[m][n][j] = 0.f; accu[m][n][j] = 0.f; }

  const int nK = H_DIM / BK; // 16
  // prologue: stage tile 0 into buffer 0
#pragma unroll
  for (int r = 0; r < 4; ++r) gload16(aS[r], smA + adst[r]);
#pragma unroll
  for (int r = 0; r < 2; ++r) {
    gload16(gS[r], smG + gdst[r]);
    gload16(uS[r], smU + gdst[r]);
  }
  __syncthreads();

  int cur = 0;
  for (int kt = 0; kt < nK; ++kt) {
    if (kt + 1 < nK) { // prefetch next K-tile into other buffer
      const int kof = (kt + 1) * BK;
      const int bA = (cur ^ 1) * 32768, bG = (cur ^ 1) * 16384;
#pragma unroll
      for (int r = 0; r < 4; ++r) gload16(aS[r] + kof, smA + bA + adst[r]);
#pragma unroll
      for (int r = 0; r < 2; ++r) {
        gload16(gS[r] + kof, smG + bG + gdst[r]);
        gload16(uS[r] + kof, smU + bG + gdst[r]);
      }
    }
    const unsigned char* A = smA + cur * 32768;
    const unsigned char* G = smG + cur * 16384;
    const unsigned char* U = smU + cur * 16384;
#pragma unroll
    for (int ks = 0; ks < 2; ++ks) {
      const int kc = ks * 64 + ((lane >> 4) * 16);
      bf16x8 a[4], bg[4], bu[4];
#pragma unroll
      for (int m = 0; m < 4; ++m)
        a[m] = *(const bf16x8*)(A + SWZ(wm * 64 + m * 16 + (lane & 15), kc));
#pragma unroll
      for (int n = 0; n < 4; ++n) {
        const int off = SWZ(wn * 64 + n * 16 + (lane & 15), kc);
        bg[n] = *(const bf16x8*)(G + off);
        bu[n] = *(const bf16x8*)(U + off);
      }
#pragma unroll
      for (int m = 0; m < 4; ++m)
#pragma unroll
        for (int n = 0; n < 4; ++n) {
          accg[m][n] = __builtin_amdgcn_mfma_f32_16x16x32_bf16(a[m], bg[n], accg[m][n], 0, 0, 0);
          accu[m][n] = __builtin_amdgcn_mfma_f32_16x16x32_bf16(a[m], bu[n], accu[m][n], 0, 0, 0);
        }
    }
    __syncthreads(); // prefetch arrived + all reads of cur done
    cur ^= 1;
  }

  // epilogue: h = silu(g)*u -> hp (bf16, permuted row layout)
#pragma unroll
  for (int m = 0; m < 4; ++m) {
    const int row0 = wm * 64 + m * 16 + (lane >> 4) * 4;
#pragma unroll
    for (int j = 0; j < 4; ++j) {
      const int gr = rowbase + row0 + j;
      if (gr < rowEnd) {
        __bf16* dst = hp + (size_t)gr * I_DIM + nbase;
#pragma unroll
        for (int n = 0; n < 4; ++n) {
          const int col = wn * 64 + n * 16 + (lane & 15);
          const float g = accg[m][n][j];
          const float u = accu[m][n][j];
          dst[col] = (__bf16)(g / (1.f + __expf(-g)) * u);
        }
      }
    }
  }
}

// =====================================================================
// pass 3: down GEMM, scatter rows to out
// BM=256 x BN=128, BK=64, prefetch double-buffered; 96KB dynamic LDS,
// 8 waves as 4(M) x 2(N), wave tile 64x64.
// =====================================================================
__global__ __launch_bounds__(512, 2) void k_down5(
    const __bf16* __restrict__ hp, const __bf16* __restrict__ wd,
    const int* __restrict__ order, const int* __restrict__ tE, const int* __restrict__ tB,
    const int* __restrict__ tEnd, const int* __restrict__ nT, float* __restrict__ out) {
  const int tile = blockIdx.y;
  if (tile >= *nT) return;
  const int e = tE[tile];
  const int rowbase = tB[tile];
  const int rowEnd = tEnd[tile];
  const int nbase = blockIdx.x * BN; // over H

  extern __shared__ __align__(16) unsigned char smem2[];
  unsigned char* smA = smem2;          // [2][32768]
  unsigned char* smB = smem2 + 65536;  // [2][16384]

  const int tid = threadIdx.x;
  const int lane = tid & 63;
  const int w = tid >> 6;
  const int wm = w & 3, wn = w >> 2; // wave tile 64 x 64

  const int lr = lane >> 3;
  const int lc = (lane & 7) ^ lr;
  const __bf16* aS[4]; const __bf16* bS[2];
  int adst[4], bdst[2];
#pragma unroll
  for (int r = 0; r < 4; ++r) {
    const int rt = r * 64 + w * 8 + lr;
    aS[r] = hp + (size_t)(rowbase + rt) * I_DIM + lc * 8;
    adst[r] = rt * 128;
  }
#pragma unroll
  for (int r = 0; r < 2; ++r) {
    const int rt = r * 64 + w * 8 + lr;
    bS[r] = wd + ((size_t)e * H_DIM + nbase + rt) * I_DIM + lc * 8;
    bdst[r] = rt * 128;
  }

  f32x4 acc[4][4];
#pragma unroll
  for (int m = 0; m < 4; ++m)
#pragma unroll
    for (int n = 0; n < 4; ++n)
#pragma unroll
      for (int j = 0; j < 4; ++j) acc[m][n][j] = 0.f;

  const int nK = I_DIM / BK; // 44
#pragma unroll
  for (int r = 0; r < 4; ++r) gload16(aS[r], smA + adst[r]);
#pragma unroll
  for (int r = 0; r < 2; ++r) gload16(bS[r], smB + bdst[r]);
  __syncthreads();

  int cur = 0;
  for (int kt = 0; kt < nK; ++kt) {
    if (kt + 1 < nK) {
      const int kof = (kt + 1) * BK;
      const int bA = (cur ^ 1) * 32768, bB = (cur ^ 1) * 16384;
#pragma unroll
      for (int r = 0; r < 4; ++r) gload16(aS[r] + kof, smA + bA + adst[r]);
#pragma unroll
      for (int r = 0; r < 2; ++r) gload16(bS[r] + kof, smB + bB + bdst[r]);
    }
    const unsigned char* A = smA + cur * 32768;
    const unsigned char* B = smB + cur * 16384;
#pragma unroll
    for (int ks = 0; ks < 2; ++ks) {
      const int kc = ks * 64 + ((lane >> 4) * 16);
      bf16x8 a[4], b[4];
#pragma unroll
      for (int m = 0; m < 4; ++m)
        a[m] = *(const bf16x8*)(A + SWZ(wm * 64 + m * 16 + (lane & 15), kc));
#pragma unroll
      for (int n = 0; n < 4; ++n)
        b[n] = *(const bf16x8*)(B + SWZ(wn * 64 + n * 16 + (lane & 15), kc));
#pragma unroll
      for (int m = 0; m < 4; ++m)
#pragma unroll
        for (int n = 0; n < 4; ++n)
          acc[m][n] = __builtin_amdgcn_mfma_f32_16x16x32_bf16(a[m], b[n], acc[m][n], 0, 0, 0);
    }
    __syncthreads();
    cur ^= 1;
  }

  // epilogue: scatter rows to out[token]
#pragma unroll
  for (int m = 0; m < 4; ++m) {
    const int row0 = wm * 64 + m * 16 + (lane >> 4) * 4;
#pragma unroll
    for (int j = 0; j < 4; ++j) {
      const int gr = rowbase + row0 + j;
      if (gr < rowEnd) {
        const int tok = order[gr];
        float* dst = out + (size_t)tok * H_DIM + nbase;
#pragma unroll
        for (int n = 0; n < 4; ++n) {
          const int col = wn * 64 + n * 16 + (lane & 15);
          dst[col] = acc[m][n][j];
        }
      }
    }
  }
}

// ---------------- launch ----------------
extern "C" void kernel_launch(void* const* d_in, const int* in_sizes, int n_in,
                              void* d_out, int out_size, void* d_ws, size_t ws_size,
                              hipStream_t stream) {
  const float* x = (const float*)d_in[0];
  const int* eidx = (const int*)d_in[1];
  const float* Wg = (const float*)d_in[2];
  const float* Wu = (const float*)d_in[3];
  const float* Wd = (const float*)d_in[4];
  float* out = (float*)d_out;

  char* ws = (char*)d_ws;
  size_t off = 0;
  auto alloc = [&](size_t bytes) -> void* {
    void* p = ws + off;
    off = (off + bytes + 255) & ~(size_t)255;
    return p;
  };
  const size_t TPAD = T_TOK + BM; // tile overreads stay within +BM rows
  __bf16* hp = (__bf16*)alloc(TPAD * I_DIM * sizeof(__bf16));
  int* order = (int*)alloc(T_TOK * sizeof(int));
  int* offsets = (int*)alloc((E_EXP + 1) * sizeof(int));
  int* tE = (int*)alloc(MAXTILES * sizeof(int));
  int* tB = (int*)alloc(MAXTILES * sizeof(int));
  int* tEnd = (int*)alloc(MAXTILES * sizeof(int));
  int* nT = (int*)alloc(sizeof(int));
  int* cc = (int*)alloc(2 * E_EXP * sizeof(int)); // counts | cursor
  int* counts = cc;
  int* cursor = cc + E_EXP;

  const size_t WSZ = (size_t)E_EXP * I_DIM * H_DIM; // elements per weight tensor
  __bf16* xp = (__bf16*)alloc(TPAD * H_DIM * sizeof(__bf16));
  __bf16* wg16 = (__bf16*)alloc(WSZ * sizeof(__bf16));
  __bf16* wu16 = (__bf16*)alloc(WSZ * sizeof(__bf16));
  __bf16* wd16 = (__bf16*)alloc(WSZ * sizeof(__bf16));

  // opt in to >64KB dynamic LDS (not a stream op; safe under graph capture)
  hipFuncSetAttribute((const void*)k_gateup5,
                      hipFuncAttributeMaxDynamicSharedMemorySize, 131072);
  hipFuncSetAttribute((const void*)k_down5,
                      hipFuncAttributeMaxDynamicSharedMemorySize, 98304);

  hipMemsetAsync(cc, 0, 2 * E_EXP * sizeof(int), stream);
  k_count<<<T_TOK / 256, 256, 0, stream>>>(eidx, counts);
  k_tiles<<<1, 1, 0, stream>>>(counts, offsets, tE, tB, tEnd, nT);
  k_scatter<<<T_TOK / 256, 256, 0, stream>>>(eidx, offsets, cursor, order);

  const int n8 = (int)(WSZ / 8);
  k_cvt<<<(n8 + 255) / 256, 256, 0, stream>>>(Wg, wg16, n8);
  k_cvt<<<(n8 + 255) / 256, 256, 0, stream>>>(Wu, wu16, n8);
  k_cvt<<<(n8 + 255) / 256, 256, 0, stream>>>(Wd, wd16, n8);
  k_xperm<<<T_TOK, 128, 0, stream>>>(x, order, xp);

  k_gateup5<<<dim3(I_DIM / BN, MAXTILES), 512, 131072, stream>>>(xp, wg16, wu16, tE, tB, tEnd, nT, hp);
  k_down5<<<dim3(H_DIM / BN, MAXTILES), 512, 98304, stream>>>(hp, wd16, order, tE, tB, tEnd, nT, out);
}

// Round 6
// 377.003 us; speedup vs baseline: 2.3716x; 1.0241x over previous
//
#include <hip/hip_runtime.h>
#include <hip/hip_bf16.h>

// Problem constants (reference: T=8192, H=1024, I=2816, E=8)
#define T_TOK 8192
#define H_DIM 1024
#define I_DIM 2816
#define E_EXP 8

#define BK 32
#define MAXT2 (T_TOK / 256 + E_EXP) // 40 (BM=256 tiles, gateup)
#define MAXT1 (T_TOK / 128 + E_EXP) // 72 (BM=128 tiles, down)

typedef __bf16 bf16x8 __attribute__((ext_vector_type(8)));
typedef float f32x4 __attribute__((ext_vector_type(4)));

// swizzled LDS byte offset, [rows][32 bf16] tile, row stride 64B.
// involution: 16B-chunk ^= (row>>1)&3  (max 2-way bank aliasing = free)
#define SWZ32(r, bc) (((r) * 64) + ((bc) ^ ((((r) >> 1) & 3) << 4)))

__device__ __forceinline__ void gload16(const void* g, void* l) {
  __builtin_amdgcn_global_load_lds((const __attribute__((address_space(1))) void*)g,
                                   (__attribute__((address_space(3))) void*)l, 16, 0, 0);
}

__device__ __forceinline__ bf16x8 cvt8(const float4& p0, const float4& p1) {
  bf16x8 v;
  v[0] = (__bf16)p0.x; v[1] = (__bf16)p0.y; v[2] = (__bf16)p0.z; v[3] = (__bf16)p0.w;
  v[4] = (__bf16)p1.x; v[5] = (__bf16)p1.y; v[6] = (__bf16)p1.z; v[7] = (__bf16)p1.w;
  return v;
}

// ---------------- bucketing kernels ----------------
__global__ void k_count(const int* __restrict__ idx, int* __restrict__ counts) {
  int t = blockIdx.x * blockDim.x + threadIdx.x;
  if (t < T_TOK) atomicAdd(&counts[idx[t]], 1);
}

__global__ void k_tiles2(const int* __restrict__ counts, int* __restrict__ offsets,
                         int* __restrict__ tE2, int* __restrict__ tB2, int* __restrict__ tEnd2,
                         int* __restrict__ nT2,
                         int* __restrict__ tE1, int* __restrict__ tB1, int* __restrict__ tEnd1,
                         int* __restrict__ nT1) {
  if (threadIdx.x != 0 || blockIdx.x != 0) return;
  int off = 0, n2 = 0, n1 = 0;
  for (int e = 0; e < E_EXP; ++e) {
    offsets[e] = off;
    int c = counts[e];
    for (int b = 0; b < c; b += 256) { tE2[n2] = e; tB2[n2] = off + b; tEnd2[n2] = off + c; ++n2; }
    for (int b = 0; b < c; b += 128) { tE1[n1] = e; tB1[n1] = off + b; tEnd1[n1] = off + c; ++n1; }
    off += c;
  }
  offsets[E_EXP] = off;
  *nT2 = n2;
  *nT1 = n1;
}

__global__ void k_scatter(const int* __restrict__ idx, const int* __restrict__ offsets,
                          int* __restrict__ cursor, int* __restrict__ order) {
  int t = blockIdx.x * blockDim.x + threadIdx.x;
  if (t < T_TOK) {
    int e = idx[t];
    int p = offsets[e] + atomicAdd(&cursor[e], 1);
    order[p] = t;
  }
}

// ---------------- bf16 pre-conversion (3 weight tensors, one launch) ----------------
__global__ __launch_bounds__(256) void k_cvt3(const float* __restrict__ s0, const float* __restrict__ s1,
                                              const float* __restrict__ s2, __bf16* __restrict__ d0,
                                              __bf16* __restrict__ d1, __bf16* __restrict__ d2, int n8each) {
  int i = blockIdx.x * blockDim.x + threadIdx.x;
  int seg = i / n8each;
  int j = i - seg * n8each;
  if (seg >= 3) return;
  const float* s = seg == 0 ? s0 : (seg == 1 ? s1 : s2);
  __bf16* d = seg == 0 ? d0 : (seg == 1 ? d1 : d2);
  const float4 p0 = ((const float4*)s)[j * 2];
  const float4 p1 = ((const float4*)s)[j * 2 + 1];
  ((bf16x8*)d)[j] = cvt8(p0, p1);
}

// gather by order + convert x -> xp (bf16, permuted rows)
__global__ __launch_bounds__(128) void k_xperm(const float* __restrict__ x,
                                               const int* __restrict__ order,
                                               __bf16* __restrict__ xp) {
  const int row = blockIdx.x;
  const int tok = order[row];
  const float* s = x + (size_t)tok * H_DIM + threadIdx.x * 8;
  const float4 p0 = ((const float4*)s)[0];
  const float4 p1 = ((const float4*)s)[1];
  *(bf16x8*)(xp + (size_t)row * H_DIM + threadIdx.x * 8) = cvt8(p0, p1);
}

// =====================================================================
// pass 2: gate/up GEMM + silu*mul -> hp
// BM=256 x BN=128, BK=32. Depth-2 pipeline: 3 LDS buffers, counted vmcnt,
// raw s_barrier (no vmcnt(0) drain in the loop). 96KB dynamic LDS.
// 8 waves as 4(M) x 2(N); wave tile 64x64 dual-op. L=4 loads/thread/step.
// =====================================================================
__global__ __launch_bounds__(512, 2) void k_gateup6(
    const __bf16* __restrict__ xp, const __bf16* __restrict__ wg, const __bf16* __restrict__ wu,
    const int* __restrict__ tE, const int* __restrict__ tB,
    const int* __restrict__ tEnd, const int* __restrict__ nT, __bf16* __restrict__ hp) {
  const int tile = blockIdx.y;
  if (tile >= *nT) return;
  const int e = tE[tile];
  const int rowbase = tB[tile];
  const int rowEnd = tEnd[tile];
  const int nbase = blockIdx.x * 128;

  extern __shared__ __align__(16) unsigned char smem[];
  unsigned char* smA = smem;          // 3 x 16384 (256 rows x 64B)
  unsigned char* smG = smem + 49152;  // 3 x 8192  (128 rows x 64B)
  unsigned char* smU = smem + 73728;  // 3 x 8192

  const int tid = threadIdx.x;
  const int lane = tid & 63;
  const int w = tid >> 6;            // 0..7
  const int wm = w & 3, wn = w >> 2; // 4 x 2 wave grid, wave tile 64x64

  // staging: row = tid>>2 (+128 for A's 2nd round), source chunk pre-swizzled
  const int srow = tid >> 2;                       // 0..127
  const int sch = (tid & 3) ^ ((tid >> 3) & 3);    // chunk ^ ((row>>1)&3)
  const __bf16* aS0 = xp + (size_t)(rowbase + srow) * H_DIM + sch * 8;
  const __bf16* aS1 = xp + (size_t)(rowbase + 128 + srow) * H_DIM + sch * 8;
  const __bf16* gS = wg + ((size_t)e * I_DIM + nbase + srow) * H_DIM + sch * 8;
  const __bf16* uS = wu + ((size_t)e * I_DIM + nbase + srow) * H_DIM + sch * 8;
  const int adst = w * 1024; // wave-uniform; HW adds lane*16

  f32x4 accg[4][4], accu[4][4];
#pragma unroll
  for (int m = 0; m < 4; ++m)
#pragma unroll
    for (int n = 0; n < 4; ++n)
#pragma unroll
      for (int j = 0; j < 4; ++j) { accg[m][n][j] = 0.f; accu[m][n][j] = 0.f; }

  auto STAGE = [&](int kt, int b) {
    const size_t kof = (size_t)kt * BK;
    gload16(aS0 + kof, smA + b * 16384 + adst);
    gload16(aS1 + kof, smA + b * 16384 + 8192 + adst);
    gload16(gS + kof, smG + b * 8192 + adst);
    gload16(uS + kof, smU + b * 8192 + adst);
  };

  const int kc = (lane >> 4) * 16; // 16B K-chunk within 64B row
  auto COMPUTE = [&](int b) {
    const unsigned char* A = smA + b * 16384;
    const unsigned char* G = smG + b * 8192;
    const unsigned char* U = smU + b * 8192;
    bf16x8 a[4], bg[4], bu[4];
#pragma unroll
    for (int m = 0; m < 4; ++m)
      a[m] = *(const bf16x8*)(A + SWZ32(wm * 64 + m * 16 + (lane & 15), kc));
#pragma unroll
    for (int n = 0; n < 4; ++n) {
      const int off = SWZ32(wn * 64 + n * 16 + (lane & 15), kc);
      bg[n] = *(const bf16x8*)(G + off);
      bu[n] = *(const bf16x8*)(U + off);
    }
#pragma unroll
    for (int m = 0; m < 4; ++m)
#pragma unroll
      for (int n = 0; n < 4; ++n) {
        accg[m][n] = __builtin_amdgcn_mfma_f32_16x16x32_bf16(a[m], bg[n], accg[m][n], 0, 0, 0);
        accu[m][n] = __builtin_amdgcn_mfma_f32_16x16x32_bf16(a[m], bu[n], accu[m][n], 0, 0, 0);
      }
  };

  const int nK = H_DIM / BK; // 32
  STAGE(0, 0);
  STAGE(1, 1);
  int b0 = 0, b1 = 1, b2 = 2;
  for (int t = 0; t < nK - 2; ++t) {
    STAGE(t + 2, b2);
    asm volatile("s_waitcnt vmcnt(8)" ::: "memory"); // tile t's 4 loads retired
    __builtin_amdgcn_s_barrier();
    __builtin_amdgcn_sched_barrier(0);
    COMPUTE(b0);
    asm volatile("s_waitcnt lgkmcnt(0)" ::: "memory");
    __builtin_amdgcn_sched_barrier(0);
    __builtin_amdgcn_s_barrier();
    const int tmp = b0; b0 = b1; b1 = b2; b2 = tmp;
  }
  // t = nK-2
  asm volatile("s_waitcnt vmcnt(4)" ::: "memory");
  __builtin_amdgcn_s_barrier();
  __builtin_amdgcn_sched_barrier(0);
  COMPUTE(b0);
  asm volatile("s_waitcnt lgkmcnt(0)" ::: "memory");
  __builtin_amdgcn_sched_barrier(0);
  __builtin_amdgcn_s_barrier();
  { const int tmp = b0; b0 = b1; b1 = b2; b2 = tmp; }
  // t = nK-1
  asm volatile("s_waitcnt vmcnt(0)" ::: "memory");
  __builtin_amdgcn_s_barrier();
  __builtin_amdgcn_sched_barrier(0);
  COMPUTE(b0);

  // epilogue: h = silu(g)*u -> hp (bf16, permuted row layout)
#pragma unroll
  for (int m = 0; m < 4; ++m) {
    const int row0 = wm * 64 + m * 16 + (lane >> 4) * 4;
#pragma unroll
    for (int j = 0; j < 4; ++j) {
      const int gr = rowbase + row0 + j;
      if (gr < rowEnd) {
        __bf16* dst = hp + (size_t)gr * I_DIM + nbase;
#pragma unroll
        for (int n = 0; n < 4; ++n) {
          const int col = wn * 64 + n * 16 + (lane & 15);
          const float g = accg[m][n][j];
          const float u = accu[m][n][j];
          dst[col] = (__bf16)(g / (1.f + __expf(-g)) * u);
        }
      }
    }
  }
}

// =====================================================================
// pass 3: down GEMM, scatter rows to out
// BM=128 x BN=128, BK=32. Same depth-2 counted-vmcnt pipeline.
// 48KB static LDS -> 3 blocks/CU. 8 waves as 2(M) x 4(N); wave tile 64x32.
// L=2 loads/thread/step.
// =====================================================================
__global__ __launch_bounds__(512, 2) void k_down6(
    const __bf16* __restrict__ hp, const __bf16* __restrict__ wd,
    const int* __restrict__ order, const int* __restrict__ tE, const int* __restrict__ tB,
    const int* __restrict__ tEnd, const int* __restrict__ nT, float* __restrict__ out) {
  const int tile = blockIdx.y;
  if (tile >= *nT) return;
  const int e = tE[tile];
  const int rowbase = tB[tile];
  const int rowEnd = tEnd[tile];
  const int nbase = blockIdx.x * 128; // over H

  __shared__ __align__(16) unsigned char smA[3 * 8192]; // 128 rows x 64B x 3
  __shared__ __align__(16) unsigned char smB[3 * 8192];

  const int tid = threadIdx.x;
  const int lane = tid & 63;
  const int w = tid >> 6;
  const int wm = w & 1, wn = w >> 1; // 2 x 4 wave grid, wave tile 64x32

  const int srow = tid >> 2; // 0..127
  const int sch = (tid & 3) ^ ((tid >> 3) & 3);
  const __bf16* aS = hp + (size_t)(rowbase + srow) * I_DIM + sch * 8;
  const __bf16* bS = wd + ((size_t)e * H_DIM + nbase + srow) * I_DIM + sch * 8;
  const int adst = w * 1024;

  f32x4 acc[4][2];
#pragma unroll
  for (int m = 0; m < 4; ++m)
#pragma unroll
    for (int n = 0; n < 2; ++n)
#pragma unroll
      for (int j = 0; j < 4; ++j) acc[m][n][j] = 0.f;

  auto STAGE = [&](int kt, int b) {
    const size_t kof = (size_t)kt * BK;
    gload16(aS + kof, smA + b * 8192 + adst);
    gload16(bS + kof, smB + b * 8192 + adst);
  };

  const int kc = (lane >> 4) * 16;
  auto COMPUTE = [&](int b) {
    const unsigned char* A = smA + b * 8192;
    const unsigned char* B = smB + b * 8192;
    bf16x8 a[4], bb[2];
#pragma unroll
    for (int m = 0; m < 4; ++m)
      a[m] = *(const bf16x8*)(A + SWZ32(wm * 64 + m * 16 + (lane & 15), kc));
#pragma unroll
    for (int n = 0; n < 2; ++n)
      bb[n] = *(const bf16x8*)(B + SWZ32(wn * 32 + n * 16 + (lane & 15), kc));
#pragma unroll
    for (int m = 0; m < 4; ++m)
#pragma unroll
      for (int n = 0; n < 2; ++n)
        acc[m][n] = __builtin_amdgcn_mfma_f32_16x16x32_bf16(a[m], bb[n], acc[m][n], 0, 0, 0);
  };

  const int nK = I_DIM / BK; // 88
  STAGE(0, 0);
  STAGE(1, 1);
  int b0 = 0, b1 = 1, b2 = 2;
  for (int t = 0; t < nK - 2; ++t) {
    STAGE(t + 2, b2);
    asm volatile("s_waitcnt vmcnt(4)" ::: "memory"); // tile t's 2 loads retired
    __builtin_amdgcn_s_barrier();
    __builtin_amdgcn_sched_barrier(0);
    COMPUTE(b0);
    asm volatile("s_waitcnt lgkmcnt(0)" ::: "memory");
    __builtin_amdgcn_sched_barrier(0);
    __builtin_amdgcn_s_barrier();
    const int tmp = b0; b0 = b1; b1 = b2; b2 = tmp;
  }
  asm volatile("s_waitcnt vmcnt(2)" ::: "memory");
  __builtin_amdgcn_s_barrier();
  __builtin_amdgcn_sched_barrier(0);
  COMPUTE(b0);
  asm volatile("s_waitcnt lgkmcnt(0)" ::: "memory");
  __builtin_amdgcn_sched_barrier(0);
  __builtin_amdgcn_s_barrier();
  { const int tmp = b0; b0 = b1; b1 = b2; b2 = tmp; }
  asm volatile("s_waitcnt vmcnt(0)" ::: "memory");
  __builtin_amdgcn_s_barrier();
  __builtin_amdgcn_sched_barrier(0);
  COMPUTE(b0);

  // epilogue: scatter rows to out[token]
#pragma unroll
  for (int m = 0; m < 4; ++m) {
    const int row0 = wm * 64 + m * 16 + (lane >> 4) * 4;
#pragma unroll
    for (int j = 0; j < 4; ++j) {
      const int gr = rowbase + row0 + j;
      if (gr < rowEnd) {
        const int tok = order[gr];
        float* dst = out + (size_t)tok * H_DIM + nbase;
#pragma unroll
        for (int n = 0; n < 2; ++n) {
          const int col = wn * 32 + n * 16 + (lane & 15);
          dst[col] = acc[m][n][j];
        }
      }
    }
  }
}

// ---------------- launch ----------------
extern "C" void kernel_launch(void* const* d_in, const int* in_sizes, int n_in,
                              void* d_out, int out_size, void* d_ws, size_t ws_size,
                              hipStream_t stream) {
  const float* x = (const float*)d_in[0];
  const int* eidx = (const int*)d_in[1];
  const float* Wg = (const float*)d_in[2];
  const float* Wu = (const float*)d_in[3];
  const float* Wd = (const float*)d_in[4];
  float* out = (float*)d_out;

  char* ws = (char*)d_ws;
  size_t off = 0;
  auto alloc = [&](size_t bytes) -> void* {
    void* p = ws + off;
    off = (off + bytes + 255) & ~(size_t)255;
    return p;
  };
  const size_t TPAD = T_TOK + 256; // tile overreads stay within +256 rows
  __bf16* hp = (__bf16*)alloc(TPAD * I_DIM * sizeof(__bf16));
  int* order = (int*)alloc(T_TOK * sizeof(int));
  int* offsets = (int*)alloc((E_EXP + 1) * sizeof(int));
  int* tE2 = (int*)alloc(MAXT2 * sizeof(int));
  int* tB2 = (int*)alloc(MAXT2 * sizeof(int));
  int* tEnd2 = (int*)alloc(MAXT2 * sizeof(int));
  int* nT2 = (int*)alloc(sizeof(int));
  int* tE1 = (int*)alloc(MAXT1 * sizeof(int));
  int* tB1 = (int*)alloc(MAXT1 * sizeof(int));
  int* tEnd1 = (int*)alloc(MAXT1 * sizeof(int));
  int* nT1 = (int*)alloc(sizeof(int));
  int* cc = (int*)alloc(2 * E_EXP * sizeof(int)); // counts | cursor
  int* counts = cc;
  int* cursor = cc + E_EXP;

  const size_t WSZ = (size_t)E_EXP * I_DIM * H_DIM; // elements per weight tensor
  __bf16* xp = (__bf16*)alloc(TPAD * H_DIM * sizeof(__bf16));
  __bf16* wg16 = (__bf16*)alloc(WSZ * sizeof(__bf16));
  __bf16* wu16 = (__bf16*)alloc(WSZ * sizeof(__bf16));
  __bf16* wd16 = (__bf16*)alloc(WSZ * sizeof(__bf16));

  // opt in to >64KB dynamic LDS (not a stream op; safe under graph capture)
  hipFuncSetAttribute((const void*)k_gateup6,
                      hipFuncAttributeMaxDynamicSharedMemorySize, 98304);

  hipMemsetAsync(cc, 0, 2 * E_EXP * sizeof(int), stream);
  k_count<<<T_TOK / 256, 256, 0, stream>>>(eidx, counts);
  k_tiles2<<<1, 1, 0, stream>>>(counts, offsets, tE2, tB2, tEnd2, nT2, tE1, tB1, tEnd1, nT1);
  k_scatter<<<T_TOK / 256, 256, 0, stream>>>(eidx, offsets, cursor, order);

  const int n8 = (int)(WSZ / 8);
  k_cvt3<<<(3 * n8 + 255) / 256, 256, 0, stream>>>(Wg, Wu, Wd, wg16, wu16, wd16, n8);
  k_xperm<<<T_TOK, 128, 0, stream>>>(x, order, xp);

  k_gateup6<<<dim3(I_DIM / 128, MAXT2), 512, 98304, stream>>>(xp, wg16, wu16, tE2, tB2, tEnd2, nT2, hp);
  k_down6<<<dim3(H_DIM / 128, MAXT1), 512, 0, stream>>>(hp, wd16, order, tE1, tB1, tEnd1, nT1, out);
}

// Round 7
// 373.004 us; speedup vs baseline: 2.3971x; 1.0107x over previous
//
#include <hip/hip_runtime.h>
#include <hip/hip_bf16.h>

// Problem constants (reference: T=8192, H=1024, I=2816, E=8)
#define T_TOK 8192
#define H_DIM 1024
#define I_DIM 2816
#define E_EXP 8

#define BK 64
#define MAXT (T_TOK / 256 + E_EXP) // 40 worst-case BM=256 tiles
#define GU_COLS (I_DIM / 128)      // 22
#define DN_COLS (H_DIM / 128)      // 8

typedef __bf16 bf16x8 __attribute__((ext_vector_type(8)));
typedef float f32x4 __attribute__((ext_vector_type(4)));

// swizzled LDS byte offset for a [rows][64 bf16] tile; row stride = 128B
#define SWZ(r, bc) (((r) * (BK * 2)) + (((bc) ^ (((r) & 7) << 4))))

__device__ __forceinline__ void gload16(const void* g, void* l) {
  __builtin_amdgcn_global_load_lds((const __attribute__((address_space(1))) void*)g,
                                   (__attribute__((address_space(3))) void*)l, 16, 0, 0);
}

__device__ __forceinline__ bf16x8 cvt8(const float4& p0, const float4& p1) {
  bf16x8 v;
  v[0] = (__bf16)p0.x; v[1] = (__bf16)p0.y; v[2] = (__bf16)p0.z; v[3] = (__bf16)p0.w;
  v[4] = (__bf16)p1.x; v[5] = (__bf16)p1.y; v[6] = (__bf16)p1.z; v[7] = (__bf16)p1.w;
  return v;
}

// bijective XCD-chunk swizzle (m204): give each XCD a CONTIGUOUS chunk of
// workgroups so co-resident blocks share operand panels in XCD-local L2.
__device__ __forceinline__ int xcd_swizzle(int id, int nwg) {
  const int q = nwg >> 3, r = nwg & 7;
  const int xcd = id & 7, j = id >> 3;
  return (xcd < r ? xcd * (q + 1) : r * (q + 1) + (xcd - r) * q) + j;
}

// ---------------- bucketing kernels ----------------
__global__ void k_count(const int* __restrict__ idx, int* __restrict__ counts) {
  int t = blockIdx.x * blockDim.x + threadIdx.x;
  if (t < T_TOK) atomicAdd(&counts[idx[t]], 1);
}

__global__ void k_tilesB(const int* __restrict__ counts, int* __restrict__ offsets,
                         int* __restrict__ tE, int* __restrict__ tB,
                         int* __restrict__ tEnd, int* __restrict__ nT) {
  if (threadIdx.x != 0 || blockIdx.x != 0) return;
  int off = 0, nt = 0;
  for (int e = 0; e < E_EXP; ++e) {
    offsets[e] = off;
    int c = counts[e];
    for (int b = 0; b < c; b += 256) { tE[nt] = e; tB[nt] = off + b; tEnd[nt] = off + c; ++nt; }
    off += c;
  }
  offsets[E_EXP] = off;
  *nT = nt;
}

__global__ void k_scatter(const int* __restrict__ idx, const int* __restrict__ offsets,
                          int* __restrict__ cursor, int* __restrict__ order) {
  int t = blockIdx.x * blockDim.x + threadIdx.x;
  if (t < T_TOK) {
    int e = idx[t];
    int p = offsets[e] + atomicAdd(&cursor[e], 1);
    order[p] = t;
  }
}

// ---------------- bf16 pre-conversion (3 weight tensors, one launch) ----------------
__global__ __launch_bounds__(256) void k_cvt3(const float* __restrict__ s0, const float* __restrict__ s1,
                                              const float* __restrict__ s2, __bf16* __restrict__ d0,
                                              __bf16* __restrict__ d1, __bf16* __restrict__ d2, int n8each) {
  int i = blockIdx.x * blockDim.x + threadIdx.x;
  int seg = i / n8each;
  int j = i - seg * n8each;
  if (seg >= 3) return;
  const float* s = seg == 0 ? s0 : (seg == 1 ? s1 : s2);
  __bf16* d = seg == 0 ? d0 : (seg == 1 ? d1 : d2);
  const float4 p0 = ((const float4*)s)[j * 2];
  const float4 p1 = ((const float4*)s)[j * 2 + 1];
  ((bf16x8*)d)[j] = cvt8(p0, p1);
}

// gather by order + convert x -> xp (bf16, permuted rows)
__global__ __launch_bounds__(128) void k_xperm(const float* __restrict__ x,
                                               const int* __restrict__ order,
                                               __bf16* __restrict__ xp) {
  const int row = blockIdx.x;
  const int tok = order[row];
  const float* s = x + (size_t)tok * H_DIM + threadIdx.x * 8;
  const float4 p0 = ((const float4*)s)[0];
  const float4 p1 = ((const float4*)s)[1];
  *(bf16x8*)(xp + (size_t)row * H_DIM + threadIdx.x * 8) = cvt8(p0, p1);
}

// =====================================================================
// pass 2: gate/up GEMM + silu*mul -> hp
// BM=256 x BN=128 dual-op, BK=64, depth-1 prefetch; 128KB dynamic LDS;
// 1D grid + XCD-chunk swizzle (same-tile column blocks co-resident per XCD
// -> A panel served from XCD-local L2).
// =====================================================================
__global__ __launch_bounds__(512, 2) void k_gateup7(
    const __bf16* __restrict__ xp, const __bf16* __restrict__ wg, const __bf16* __restrict__ wu,
    const int* __restrict__ tE, const int* __restrict__ tB,
    const int* __restrict__ tEnd, const int* __restrict__ nT, __bf16* __restrict__ hp) {
  const int nwg = *nT * GU_COLS;
  const int id = blockIdx.x;
  if (id >= nwg) return;
  const int wgid = xcd_swizzle(id, nwg);
  const int tile = wgid / GU_COLS;
  const int col = wgid - tile * GU_COLS;
  const int e = tE[tile];
  const int rowbase = tB[tile];
  const int rowEnd = tEnd[tile];
  const int nbase = col * 128;

  extern __shared__ __align__(16) unsigned char smem[];
  unsigned char* smA = smem;          // [2][32768]  256 x 128B
  unsigned char* smG = smem + 65536;  // [2][16384]  128 x 128B
  unsigned char* smU = smem + 98304;  // [2][16384]

  const int tid = threadIdx.x;
  const int lane = tid & 63;
  const int w = tid >> 6;            // 0..7
  const int wm = w & 3, wn = w >> 2; // 4 x 2 wave grid, wave tile 64x64

  const int lr = lane >> 3;
  const int lc = (lane & 7) ^ lr;    // pre-swizzled global 16B chunk
  const __bf16* aS[4]; const __bf16* gS[2]; const __bf16* uS[2];
  int adst[4], gdst[2];
#pragma unroll
  for (int r = 0; r < 4; ++r) { // A: 256 rows in 4 rounds of 64
    const int rt = r * 64 + w * 8 + lr;
    aS[r] = xp + (size_t)(rowbase + rt) * H_DIM + lc * 8;
    adst[r] = rt * 128;
  }
#pragma unroll
  for (int r = 0; r < 2; ++r) { // G/U: 128 rows in 2 rounds of 64
    const int rt = r * 64 + w * 8 + lr;
    gS[r] = wg + ((size_t)e * I_DIM + nbase + rt) * H_DIM + lc * 8;
    uS[r] = wu + ((size_t)e * I_DIM + nbase + rt) * H_DIM + lc * 8;
    gdst[r] = rt * 128;
  }

  f32x4 accg[4][4], accu[4][4];
#pragma unroll
  for (int m = 0; m < 4; ++m)
#pragma unroll
    for (int n = 0; n < 4; ++n)
#pragma unroll
      for (int j = 0; j < 4; ++j) { accg[m][n][j] = 0.f; accu[m][n][j] = 0.f; }

  const int nK = H_DIM / BK; // 16
#pragma unroll
  for (int r = 0; r < 4; ++r) gload16(aS[r], smA + adst[r]);
#pragma unroll
  for (int r = 0; r < 2; ++r) {
    gload16(gS[r], smG + gdst[r]);
    gload16(uS[r], smU + gdst[r]);
  }
  __syncthreads();

  int cur = 0;
  for (int kt = 0; kt < nK; ++kt) {
    if (kt + 1 < nK) { // prefetch next K-tile into other buffer
      const int kof = (kt + 1) * BK;
      const int bA = (cur ^ 1) * 32768, bG = (cur ^ 1) * 16384;
#pragma unroll
      for (int r = 0; r < 4; ++r) gload16(aS[r] + kof, smA + bA + adst[r]);
#pragma unroll
      for (int r = 0; r < 2; ++r) {
        gload16(gS[r] + kof, smG + bG + gdst[r]);
        gload16(uS[r] + kof, smU + bG + gdst[r]);
      }
    }
    const unsigned char* A = smA + cur * 32768;
    const unsigned char* G = smG + cur * 16384;
    const unsigned char* U = smU + cur * 16384;
#pragma unroll
    for (int ks = 0; ks < 2; ++ks) {
      const int kc = ks * 64 + ((lane >> 4) * 16);
      bf16x8 a[4], bg[4], bu[4];
#pragma unroll
      for (int m = 0; m < 4; ++m)
        a[m] = *(const bf16x8*)(A + SWZ(wm * 64 + m * 16 + (lane & 15), kc));
#pragma unroll
      for (int n = 0; n < 4; ++n) {
        const int off = SWZ(wn * 64 + n * 16 + (lane & 15), kc);
        bg[n] = *(const bf16x8*)(G + off);
        bu[n] = *(const bf16x8*)(U + off);
      }
#pragma unroll
      for (int m = 0; m < 4; ++m)
#pragma unroll
        for (int n = 0; n < 4; ++n) {
          accg[m][n] = __builtin_amdgcn_mfma_f32_16x16x32_bf16(a[m], bg[n], accg[m][n], 0, 0, 0);
          accu[m][n] = __builtin_amdgcn_mfma_f32_16x16x32_bf16(a[m], bu[n], accu[m][n], 0, 0, 0);
        }
    }
    __syncthreads();
    cur ^= 1;
  }

  // epilogue: h = silu(g)*u -> hp (bf16, permuted row layout)
#pragma unroll
  for (int m = 0; m < 4; ++m) {
    const int row0 = wm * 64 + m * 16 + (lane >> 4) * 4;
#pragma unroll
    for (int j = 0; j < 4; ++j) {
      const int gr = rowbase + row0 + j;
      if (gr < rowEnd) {
        __bf16* dst = hp + (size_t)gr * I_DIM + nbase;
#pragma unroll
        for (int n = 0; n < 4; ++n) {
          const int c2 = wn * 64 + n * 16 + (lane & 15);
          const float g = accg[m][n][j];
          const float u = accu[m][n][j];
          dst[c2] = (__bf16)(g / (1.f + __expf(-g)) * u);
        }
      }
    }
  }
}

// =====================================================================
// pass 3: down GEMM, scatter rows to out
// BM=256 x BN=128, BK=64, depth-1 prefetch; 96KB dynamic LDS;
// 1D grid + XCD-chunk swizzle (hp panel L2-resident across the 8 H-columns).
// =====================================================================
__global__ __launch_bounds__(512, 2) void k_down7(
    const __bf16* __restrict__ hp, const __bf16* __restrict__ wd,
    const int* __restrict__ order, const int* __restrict__ tE, const int* __restrict__ tB,
    const int* __restrict__ tEnd, const int* __restrict__ nT, float* __restrict__ out) {
  const int nwg = *nT * DN_COLS;
  const int id = blockIdx.x;
  if (id >= nwg) return;
  const int wgid = xcd_swizzle(id, nwg);
  const int tile = wgid >> 3;
  const int col = wgid & 7;
  const int e = tE[tile];
  const int rowbase = tB[tile];
  const int rowEnd = tEnd[tile];
  const int nbase = col * 128; // over H

  extern __shared__ __align__(16) unsigned char smem2[];
  unsigned char* smA = smem2;          // [2][32768]  256 x 128B
  unsigned char* smB = smem2 + 65536;  // [2][16384]  128 x 128B

  const int tid = threadIdx.x;
  const int lane = tid & 63;
  const int w = tid >> 6;
  const int wm = w & 3, wn = w >> 2; // 4 x 2 wave grid, wave tile 64x64

  const int lr = lane >> 3;
  const int lc = (lane & 7) ^ lr;
  const __bf16* aS[4]; const __bf16* bS[2];
  int adst[4], bdst[2];
#pragma unroll
  for (int r = 0; r < 4; ++r) {
    const int rt = r * 64 + w * 8 + lr;
    aS[r] = hp + (size_t)(rowbase + rt) * I_DIM + lc * 8;
    adst[r] = rt * 128;
  }
#pragma unroll
  for (int r = 0; r < 2; ++r) {
    const int rt = r * 64 + w * 8 + lr;
    bS[r] = wd + ((size_t)e * H_DIM + nbase + rt) * I_DIM + lc * 8;
    bdst[r] = rt * 128;
  }

  f32x4 acc[4][4];
#pragma unroll
  for (int m = 0; m < 4; ++m)
#pragma unroll
    for (int n = 0; n < 4; ++n)
#pragma unroll
      for (int j = 0; j < 4; ++j) acc[m][n][j] = 0.f;

  const int nK = I_DIM / BK; // 44
#pragma unroll
  for (int r = 0; r < 4; ++r) gload16(aS[r], smA + adst[r]);
#pragma unroll
  for (int r = 0; r < 2; ++r) gload16(bS[r], smB + bdst[r]);
  __syncthreads();

  int cur = 0;
  for (int kt = 0; kt < nK; ++kt) {
    if (kt + 1 < nK) {
      const int kof = (kt + 1) * BK;
      const int bA = (cur ^ 1) * 32768, bB = (cur ^ 1) * 16384;
#pragma unroll
      for (int r = 0; r < 4; ++r) gload16(aS[r] + kof, smA + bA + adst[r]);
#pragma unroll
      for (int r = 0; r < 2; ++r) gload16(bS[r] + kof, smB + bB + bdst[r]);
    }
    const unsigned char* A = smA + cur * 32768;
    const unsigned char* B = smB + cur * 16384;
#pragma unroll
    for (int ks = 0; ks < 2; ++ks) {
      const int kc = ks * 64 + ((lane >> 4) * 16);
      bf16x8 a[4], b[4];
#pragma unroll
      for (int m = 0; m < 4; ++m)
        a[m] = *(const bf16x8*)(A + SWZ(wm * 64 + m * 16 + (lane & 15), kc));
#pragma unroll
      for (int n = 0; n < 4; ++n)
        b[n] = *(const bf16x8*)(B + SWZ(wn * 64 + n * 16 + (lane & 15), kc));
#pragma unroll
      for (int m = 0; m < 4; ++m)
#pragma unroll
        for (int n = 0; n < 4; ++n)
          acc[m][n] = __builtin_amdgcn_mfma_f32_16x16x32_bf16(a[m], b[n], acc[m][n], 0, 0, 0);
    }
    __syncthreads();
    cur ^= 1;
  }

  // epilogue: scatter rows to out[token]
#pragma unroll
  for (int m = 0; m < 4; ++m) {
    const int row0 = wm * 64 + m * 16 + (lane >> 4) * 4;
#pragma unroll
    for (int j = 0; j < 4; ++j) {
      const int gr = rowbase + row0 + j;
      if (gr < rowEnd) {
        const int tok = order[gr];
        float* dst = out + (size_t)tok * H_DIM + nbase;
#pragma unroll
        for (int n = 0; n < 4; ++n) {
          const int c2 = wn * 64 + n * 16 + (lane & 15);
          dst[c2] = acc[m][n][j];
        }
      }
    }
  }
}

// ---------------- launch ----------------
extern "C" void kernel_launch(void* const* d_in, const int* in_sizes, int n_in,
                              void* d_out, int out_size, void* d_ws, size_t ws_size,
                              hipStream_t stream) {
  const float* x = (const float*)d_in[0];
  const int* eidx = (const int*)d_in[1];
  const float* Wg = (const float*)d_in[2];
  const float* Wu = (const float*)d_in[3];
  const float* Wd = (const float*)d_in[4];
  float* out = (float*)d_out;

  char* ws = (char*)d_ws;
  size_t off = 0;
  auto alloc = [&](size_t bytes) -> void* {
    void* p = ws + off;
    off = (off + bytes + 255) & ~(size_t)255;
    return p;
  };
  const size_t TPAD = T_TOK + 256; // tile overreads stay within +256 rows
  __bf16* hp = (__bf16*)alloc(TPAD * I_DIM * sizeof(__bf16));
  int* order = (int*)alloc(T_TOK * sizeof(int));
  int* offsets = (int*)alloc((E_EXP + 1) * sizeof(int));
  int* tE = (int*)alloc(MAXT * sizeof(int));
  int* tB = (int*)alloc(MAXT * sizeof(int));
  int* tEnd = (int*)alloc(MAXT * sizeof(int));
  int* nT = (int*)alloc(sizeof(int));
  int* cc = (int*)alloc(2 * E_EXP * sizeof(int)); // counts | cursor
  int* counts = cc;
  int* cursor = cc + E_EXP;

  const size_t WSZ = (size_t)E_EXP * I_DIM * H_DIM; // elements per weight tensor
  __bf16* xp = (__bf16*)alloc(TPAD * H_DIM * sizeof(__bf16));
  __bf16* wg16 = (__bf16*)alloc(WSZ * sizeof(__bf16));
  __bf16* wu16 = (__bf16*)alloc(WSZ * sizeof(__bf16));
  __bf16* wd16 = (__bf16*)alloc(WSZ * sizeof(__bf16));

  // opt in to >64KB dynamic LDS (not a stream op; safe under graph capture)
  hipFuncSetAttribute((const void*)k_gateup7,
                      hipFuncAttributeMaxDynamicSharedMemorySize, 131072);
  hipFuncSetAttribute((const void*)k_down7,
                      hipFuncAttributeMaxDynamicSharedMemorySize, 98304);

  hipMemsetAsync(cc, 0, 2 * E_EXP * sizeof(int), stream);
  k_count<<<T_TOK / 256, 256, 0, stream>>>(eidx, counts);
  k_tilesB<<<1, 1, 0, stream>>>(counts, offsets, tE, tB, tEnd, nT);
  k_scatter<<<T_TOK / 256, 256, 0, stream>>>(eidx, offsets, cursor, order);

  const int n8 = (int)(WSZ / 8);
  k_cvt3<<<(3 * n8 + 255) / 256, 256, 0, stream>>>(Wg, Wu, Wd, wg16, wu16, wd16, n8);
  k_xperm<<<T_TOK, 128, 0, stream>>>(x, order, xp);

  k_gateup7<<<GU_COLS * MAXT, 512, 131072, stream>>>(xp, wg16, wu16, tE, tB, tEnd, nT, hp);
  k_down7<<<DN_COLS * MAXT, 512, 98304, stream>>>(hp, wd16, order, tE, tB, tEnd, nT, out);
}